// Round 1
// 252.723 us; speedup vs baseline: 1.0151x; 1.0151x over previous
//
#include <hip/hip_runtime.h>
#include <cstddef>

#define NN   50000
#define KNB  32

typedef _Float16 h2    __attribute__((ext_vector_type(2)));
typedef _Float16 half8 __attribute__((ext_vector_type(8)));
typedef float    f4    __attribute__((ext_vector_type(4)));
typedef float    f8    __attribute__((ext_vector_type(8)));

// ---------------- prep: W1^T and W2^T as fp16 [N][K] ----------------------
__global__ __launch_bounds__(256) void prep(const float* __restrict__ W1,
                                            const float* __restrict__ W2,
                                            _Float16* __restrict__ w1t,
                                            _Float16* __restrict__ w2t) {
  const int id = blockIdx.x * 256 + threadIdx.x;
  if (id < 128 * 512) {                     // w1t[n][k] = W1[k][n]
    const int n = id >> 9, k = id & 511;
    w1t[id] = (_Float16)W1[k * 128 + n];
  } else {
    const int id2 = id - 128 * 512;
    if (id2 < 64 * 128) {                   // w2t[n][k] = W2[k][n]
      const int n = id2 >> 7, k = id2 & 127;
      w2t[id2] = (_Float16)W2[k * 64 + n];
    }
  }
}

// ---------------- GEMM1: H1[M,128] = A[M,512]fp32 @ W1 + b1, fp16 out -----
// R8: LDS-staged (m97 pattern), verified. Unchanged this round (R9 touches
// medians only, for attribution).
__global__ __launch_bounds__(256) void gemm1_mfma(
    const float* __restrict__ A, const _Float16* __restrict__ Bt,
    const float* __restrict__ bias, _Float16* __restrict__ C, int M) {
  constexpr int K = 512, BM = 64, BK = 32;
  __shared__ _Float16 Ah[BM][40];     // 5 KB, 80B stride
  __shared__ _Float16 Bh[128][40];    // 10 KB
  const int tid  = threadIdx.x;
  const int wave = tid >> 6;
  const int lane = tid & 63;
  const int mr   = lane & 15;
  const int kg   = lane >> 4;
  const int m0   = blockIdx.x * BM;

  const int srow = tid >> 2;          // 0..63
  const int sseg = (tid & 3) * 8;     // elem offset 0,8,16,24
  int aRow = m0 + srow;
  if (aRow >= M) aRow = M - 1;        // clamp; garbage rows dropped at store
  const float*    ap  = A  + (size_t)aRow * K + sseg;
  const _Float16* bp0 = Bt + (size_t)srow * K + sseg;          // rows 0..63
  const _Float16* bp1 = Bt + (size_t)(64 + srow) * K + sseg;   // rows 64..127

  f4 acc[8] = {};

  for (int k0 = 0; k0 < K; k0 += BK) {
    const f4 t0 = *(const f4*)ap;
    const f4 t1 = *(const f4*)(ap + 4);
    const half8 blo = *(const half8*)bp0;
    const half8 bhi = *(const half8*)bp1;
    const f8 av = {t0[0], t0[1], t0[2], t0[3], t1[0], t1[1], t1[2], t1[3]};
    *(half8*)&Ah[srow][sseg]      = __builtin_convertvector(av, half8);
    *(half8*)&Bh[srow][sseg]      = blo;
    *(half8*)&Bh[64 + srow][sseg] = bhi;
    __syncthreads();

    const half8 af = *(const half8*)&Ah[wave * 16 + mr][kg * 8];
    #pragma unroll
    for (int nt = 0; nt < 8; ++nt) {
      const half8 bf = *(const half8*)&Bh[nt * 16 + mr][kg * 8];
      acc[nt] = __builtin_amdgcn_mfma_f32_16x16x32_f16(af, bf, acc[nt], 0, 0, 0);
    }
    __syncthreads();
    ap += BK;
    bp0 += BK;
    bp1 += BK;
  }

  #pragma unroll
  for (int nt = 0; nt < 8; ++nt) {
    const int col = nt * 16 + mr;
    const float bv = bias[col];
    #pragma unroll
    for (int r = 0; r < 4; ++r) {
      const int row = m0 + wave * 16 + kg * 4 + r;
      if (row < M)
        C[(size_t)row * 128 + col] = (_Float16)(acc[nt][r] + bv);
    }
  }
}

// ---------------- GEMM2: H2[M,64] = A[M,128]fp16 @ W2 + b2, fp16 out ------
__global__ __launch_bounds__(256) void gemm2_mfma(
    const _Float16* __restrict__ A, const _Float16* __restrict__ Bt,
    const float* __restrict__ bias, _Float16* __restrict__ C, int M) {
  constexpr int K = 128, BM = 64, BK = 32;
  __shared__ _Float16 Ah[BM][40];     // 5 KB
  __shared__ _Float16 Bh[64][40];     // 5 KB
  const int tid  = threadIdx.x;
  const int wave = tid >> 6;
  const int lane = tid & 63;
  const int mr   = lane & 15;
  const int kg   = lane >> 4;
  const int m0   = blockIdx.x * BM;

  const int srow = tid >> 2;          // 0..63
  const int sseg = (tid & 3) * 8;
  int aRow = m0 + srow;
  if (aRow >= M) aRow = M - 1;
  const _Float16* ap = A  + (size_t)aRow * K + sseg;
  const _Float16* bp = Bt + (size_t)srow * K + sseg;

  f4 acc[4] = {};

  #pragma unroll
  for (int k0 = 0; k0 < K; k0 += BK) {
    *(half8*)&Ah[srow][sseg] = *(const half8*)ap;
    *(half8*)&Bh[srow][sseg] = *(const half8*)bp;
    __syncthreads();

    const half8 af = *(const half8*)&Ah[wave * 16 + mr][kg * 8];
    #pragma unroll
    for (int nt = 0; nt < 4; ++nt) {
      const half8 bf = *(const half8*)&Bh[nt * 16 + mr][kg * 8];
      acc[nt] = __builtin_amdgcn_mfma_f32_16x16x32_f16(af, bf, acc[nt], 0, 0, 0);
    }
    __syncthreads();
    ap += BK;
    bp += BK;
  }

  #pragma unroll
  for (int nt = 0; nt < 4; ++nt) {
    const int col = nt * 16 + mr;
    const float bv = bias[col];
    #pragma unroll
    for (int r = 0; r < 4; ++r) {
      const int row = m0 + wave * 16 + kg * 4 + r;
      if (row < M)
        C[(size_t)row * 64 + col] = (_Float16)(acc[nt][r] + bv);
    }
  }
}

// ---------------- median machinery ----------------------------------------
__device__ __forceinline__ void ceh(h2& a, h2& b) {
  h2 lo = __builtin_elementwise_min(a, b);
  h2 hi = __builtin_elementwise_max(a, b);
  a = lo;
  b = hi;
}

// Batcher odd-even mergesort over NE packed-h2 elements (NE = power of 2).
template <int NE>
__device__ __forceinline__ void sortNh(h2* v) {
  #pragma unroll
  for (int p = 1; p < NE; p <<= 1) {
    #pragma unroll
    for (int k = p; k >= 1; k >>= 1) {
      #pragma unroll
      for (int j = k & (p - 1); j + k < NE; j += 2 * k) {
        #pragma unroll
        for (int i = 0; i < k; ++i) {
          if (i + j + k < NE) {
            if ((i + j) / (2 * p) == (i + j + k) / (2 * p)) {
              ceh(v[i + j], v[i + j + k]);
            }
          }
        }
      }
    }
  }
}

// R9: exact lower-median of 32 via merge-select instead of full sort-32.
// Sort halves A=v[0..15], B=v[16..31] (2x63 comparators = 252 pk-ops), then
// 16th-smallest of two sorted arrays = min over splits of max(last taken):
//   med = min( A[15], B[15], max(A[i], B[14-i]) for i=0..14 )   (31 pk-ops)
// Proof: every candidate has >=16 elements <= it; the optimal split attains
// the 16th smallest. Pure fp16 min/max selection -> bit-exact vs sort.
__device__ __forceinline__ h2 median32h(h2* v) {
  sortNh<16>(v);
  sortNh<16>(v + 16);
  h2 m = __builtin_elementwise_min(v[15], v[31]);
  #pragma unroll
  for (int i = 0; i < 15; ++i) {
    m = __builtin_elementwise_min(
        m, __builtin_elementwise_max(v[i], v[30 - i]));
  }
  return m;
}

// Median over 32 neighbor rows (layer 1, D=128) + ReLU.
// R9: D-sliced into 2 passes of 64 dims (blockIdx.y). Per-slice gather
// footprint 6.4 MB (was 12.8) -> ~2x the per-XCD-L2 hit rate. Segments stay
// 128 B (32 lanes x 4 B per node), so L2 line-request count is unchanged.
// Wave = 2 nodes x 32 lanes; block = 8 nodes; x-major dispatch keeps slices
// temporally grouped (perf heuristic only, no correctness dependence).
__global__ __launch_bounds__(256) void median_relu1(const h2* __restrict__ H,
                                                    const int* __restrict__ nb,
                                                    h2* __restrict__ O) {
  const int lane = threadIdx.x & 63;
  const int node = blockIdx.x * 8 + ((threadIdx.x >> 6) << 1) + (lane >> 5);
  const int col  = blockIdx.y * 32 + (lane & 31);   // h2 column 0..63
  const int* nrow = nb + (size_t)node * KNB;
  h2 v[32];
  #pragma unroll
  for (int j = 0; j < KNB; ++j) {
    const int idx = nrow[j];
    v[j] = H[(size_t)idx * 64 + col];
  }
  const h2 med = median32h(v);
  const h2 z = (h2)((_Float16)0);
  O[(size_t)node * 64 + col] = __builtin_elementwise_max(med, z);
}

// Median over 32 neighbor rows (layer 2, D=64); fp32 output.
// Footprint already 6.4 MB with full-row 128 B segments; unsliced (slicing
// would shrink segments to 64 B and risk doubling line requests).
__global__ __launch_bounds__(256) void median2(const h2* __restrict__ H,
                                               const int* __restrict__ nb,
                                               float2* __restrict__ O) {
  const int node = blockIdx.x * 8 + (threadIdx.x >> 5);
  const int lane = threadIdx.x & 31;
  const int* nrow = nb + (size_t)node * KNB;
  h2 v[32];
  #pragma unroll
  for (int j = 0; j < KNB; ++j) {
    const int idx = nrow[j];
    v[j] = H[(size_t)idx * 32 + lane];
  }
  const h2 med = median32h(v);
  float2 o;
  o.x = (float)med[0];
  o.y = (float)med[1];
  O[(size_t)node * 32 + lane] = o;
}

extern "C" void kernel_launch(void* const* d_in, const int* in_sizes, int n_in,
                              void* d_out, int out_size, void* d_ws, size_t ws_size,
                              hipStream_t stream) {
  const float* feat = (const float*)d_in[0];   // [50000,512]
  const float* W1   = (const float*)d_in[1];   // [512,128]
  const float* b1   = (const float*)d_in[2];   // [128]
  const float* W2   = (const float*)d_in[3];   // [128,64]
  const float* b2   = (const float*)d_in[4];   // [64]
  const int*   nb   = (const int*)d_in[5];     // [50000,32]
  float* out = (float*)d_out;                  // [50000,64] fp32

  _Float16* h1   = (_Float16*)d_ws;                 // 12.8 MB
  _Float16* med1 = h1 + (size_t)NN * 128;           // 12.8 MB
  _Float16* w1t  = med1 + (size_t)NN * 128;         // 128 KB  [128][512]
  _Float16* w2t  = w1t + 128 * 512;                 // 16 KB   [64][128]
  _Float16* h2b  = h1;                              // reuse (h1 dead)

  prep<<<dim3(288), dim3(256), 0, stream>>>(W1, W2, w1t, w2t);
  gemm1_mfma<<<dim3((NN + 63) / 64), dim3(256), 0, stream>>>(feat, w1t, b1, h1, NN);
  median_relu1<<<dim3(NN / 8, 2), dim3(256), 0, stream>>>(
      (const h2*)h1, nb, (h2*)med1);
  gemm2_mfma<<<dim3((NN + 63) / 64), dim3(256), 0, stream>>>(med1, w2t, b2, h2b, NN);
  median2<<<dim3(NN / 8), dim3(256), 0, stream>>>(
      (const h2*)h2b, nb, (float2*)out);
}